// Round 2
// 949.148 us; speedup vs baseline: 1.1172x; 1.1172x over previous
//
#include <hip/hip_runtime.h>

#define H 256
#define Bg 1024
#define EPSV 1e-5f

// Native vector type: __builtin_nontemporal_* requires scalar/native-vector,
// not HIP's float4 class.
typedef float fvec4 __attribute__((ext_vector_type(4)));

__device__ __forceinline__ int lower_bound_dev(const int* __restrict__ a, int n, int key) {
    int lo = 0, hi = n;
    while (lo < hi) {
        int mid = (lo + hi) >> 1;
        if (a[mid] < key) lo = mid + 1; else hi = mid;
    }
    return lo;
}

// K1: one block per graph. Binary-search segment bounds in sorted batch_idx,
// float4-coalesced column sums with 4-deep ILP (4 independent accumulators,
// 4 outstanding loads/thread -> 64KB in flight per CU), + virtual_node -> h0.
// Block 0 zeroes BN stat accum (safe: atomics only happen in K2, next launch).
__global__ void __launch_bounds__(256) seg_sum_k(const float* __restrict__ x,
                                                 const int* __restrict__ bidx,
                                                 const float* __restrict__ vnode,
                                                 float* __restrict__ h0,
                                                 float* __restrict__ colsum,
                                                 float* __restrict__ colsumsq,
                                                 int N) {
    const int b = blockIdx.x;
    const int t = threadIdx.x;
    if (b == 0) { colsum[t] = 0.0f; colsumsq[t] = 0.0f; }

    const int start = lower_bound_dev(bidx, N, b);
    const int end   = lower_bound_dev(bidx, N, b + 1);

    const int sub = t >> 6;          // 0..3 : row phase (uniform per wave)
    const int c4  = (t & 63) << 2;   // column group (float4)
    const float* __restrict__ xp = x + c4;

    fvec4 a0 = (fvec4)0.0f;
    fvec4 a1 = a0, a2 = a0, a3 = a0;

    int r = start + sub;
    // 4-deep unroll: rows r, r+4, r+8, r+12 (stride 4 = phase stride).
    for (; r + 12 < end; r += 16) {
        const fvec4 v0 = __builtin_nontemporal_load(
            reinterpret_cast<const fvec4*>(xp + (size_t)r * H));
        const fvec4 v1 = __builtin_nontemporal_load(
            reinterpret_cast<const fvec4*>(xp + (size_t)(r + 4) * H));
        const fvec4 v2 = __builtin_nontemporal_load(
            reinterpret_cast<const fvec4*>(xp + (size_t)(r + 8) * H));
        const fvec4 v3 = __builtin_nontemporal_load(
            reinterpret_cast<const fvec4*>(xp + (size_t)(r + 12) * H));
        a0 += v0; a1 += v1; a2 += v2; a3 += v3;
    }
    for (; r < end; r += 4) {
        const fvec4 v = __builtin_nontemporal_load(
            reinterpret_cast<const fvec4*>(xp + (size_t)r * H));
        a0 += v;
    }

    const fvec4 acc = (a0 + a1) + (a2 + a3);

    __shared__ fvec4 red[256];
    red[t] = acc;
    __syncthreads();
    if (sub == 0) {
        fvec4 s0 = red[t];
        const fvec4 s1 = red[t + 64];
        const fvec4 s2 = red[t + 128];
        const fvec4 s3 = red[t + 192];
        const fvec4 vn = *reinterpret_cast<const fvec4*>(vnode + (size_t)b * H + c4);
        s0 = s0 + s1 + s2 + s3 + vn;
        *reinterpret_cast<fvec4*>(h0 + (size_t)b * H + c4) = s0;
    }
}

// K2: h1 = h0 @ W1 + b1 ([1024,256]x[256,256]); 4 rows per block, W1 streamed
// coalesced (L2-resident, 256KB). Also accumulates BN column sum / sumsq.
__global__ void __launch_bounds__(256) gemm1_k(const float* __restrict__ h0,
                                               const float* __restrict__ W1,
                                               const float* __restrict__ b1,
                                               float* __restrict__ h1,
                                               float* __restrict__ colsum,
                                               float* __restrict__ colsumsq) {
    __shared__ float a[4][H];
    const int t = threadIdx.x;
    const int r0 = blockIdx.x << 2;
#pragma unroll
    for (int i = 0; i < 4; ++i) a[i][t] = h0[(size_t)(r0 + i) * H + t];
    __syncthreads();

    const float bb = b1[t];
    float acc0 = bb, acc1 = bb, acc2 = bb, acc3 = bb;
#pragma unroll 8
    for (int k = 0; k < H; ++k) {
        const float w = W1[(size_t)k * H + t];   // coalesced across t, broadcast a[][k]
        acc0 = fmaf(a[0][k], w, acc0);
        acc1 = fmaf(a[1][k], w, acc1);
        acc2 = fmaf(a[2][k], w, acc2);
        acc3 = fmaf(a[3][k], w, acc3);
    }
    h1[(size_t)(r0 + 0) * H + t] = acc0;
    h1[(size_t)(r0 + 1) * H + t] = acc1;
    h1[(size_t)(r0 + 2) * H + t] = acc2;
    h1[(size_t)(r0 + 3) * H + t] = acc3;

    const float s  = acc0 + acc1 + acc2 + acc3;
    const float sq = acc0 * acc0 + acc1 * acc1 + acc2 * acc2 + acc3 * acc3;
    atomicAdd(&colsum[t], s);
    atomicAdd(&colsumsq[t], sq);
}

// K3: vn = relu(BN(h1)) @ W2 + b2. BN applied on the fly from colsum/colsumsq.
// vn written directly to d_out's second output slot.
__global__ void __launch_bounds__(256) gemm2_k(const float* __restrict__ h1,
                                               const float* __restrict__ colsum,
                                               const float* __restrict__ colsumsq,
                                               const float* __restrict__ gamma,
                                               const float* __restrict__ beta,
                                               const float* __restrict__ W2,
                                               const float* __restrict__ b2,
                                               float* __restrict__ out_vn) {
    __shared__ float a[4][H];
    const int t = threadIdx.x;
    const int r0 = blockIdx.x << 2;

    const float invB = 1.0f / (float)Bg;
    const float m   = colsum[t] * invB;
    const float var = colsumsq[t] * invB - m * m;
    const float g   = gamma[t] * rsqrtf(var + EPSV);
    const float be  = beta[t];

#pragma unroll
    for (int i = 0; i < 4; ++i) {
        float v = h1[(size_t)(r0 + i) * H + t];
        v = (v - m) * g + be;
        a[i][t] = fmaxf(v, 0.0f);
    }
    __syncthreads();

    const float bb = b2[t];
    float acc0 = bb, acc1 = bb, acc2 = bb, acc3 = bb;
#pragma unroll 8
    for (int k = 0; k < H; ++k) {
        const float w = W2[(size_t)k * H + t];
        acc0 = fmaf(a[0][k], w, acc0);
        acc1 = fmaf(a[1][k], w, acc1);
        acc2 = fmaf(a[2][k], w, acc2);
        acc3 = fmaf(a[3][k], w, acc3);
    }
    out_vn[(size_t)(r0 + 0) * H + t] = acc0;
    out_vn[(size_t)(r0 + 1) * H + t] = acc1;
    out_vn[(size_t)(r0 + 2) * H + t] = acc2;
    out_vn[(size_t)(r0 + 3) * H + t] = acc3;
}

// K4: x_out = x + vn[batch_idx]. Contiguous row chunks per block, float4,
// 2-deep ILP (both x loads + both vn loads issued before any adds/stores).
// Nontemporal x read / x_out write (no reuse; 512MB >> L3). vn stays cached.
__global__ void __launch_bounds__(256) gather_add_k(const float* __restrict__ x,
                                                    const int* __restrict__ bidx,
                                                    const float* __restrict__ vn,
                                                    float* __restrict__ xout,
                                                    int N, int rpb) {
    const int t = threadIdx.x;
    const int r0 = blockIdx.x * rpb;
    const int r1 = min(N, r0 + rpb);
    const int sub = t >> 6;          // uniform per wave
    const int c4  = (t & 63) << 2;
    const float* __restrict__ xp = x + c4;
    float* __restrict__ op = xout + c4;

    int r = r0 + sub;
    for (; r + 4 < r1; r += 8) {
        const int b0 = bidx[r];
        const int b1 = bidx[r + 4];
        fvec4 x0 = __builtin_nontemporal_load(
            reinterpret_cast<const fvec4*>(xp + (size_t)r * H));
        fvec4 x1 = __builtin_nontemporal_load(
            reinterpret_cast<const fvec4*>(xp + (size_t)(r + 4) * H));
        const fvec4 v0 = *reinterpret_cast<const fvec4*>(vn + (size_t)b0 * H + c4);
        const fvec4 v1 = *reinterpret_cast<const fvec4*>(vn + (size_t)b1 * H + c4);
        x0 += v0;
        x1 += v1;
        __builtin_nontemporal_store(x0, reinterpret_cast<fvec4*>(op + (size_t)r * H));
        __builtin_nontemporal_store(x1, reinterpret_cast<fvec4*>(op + (size_t)(r + 4) * H));
    }
    if (r < r1) {
        const int b = bidx[r];
        fvec4 xv = __builtin_nontemporal_load(
            reinterpret_cast<const fvec4*>(xp + (size_t)r * H));
        const fvec4 vv = *reinterpret_cast<const fvec4*>(vn + (size_t)b * H + c4);
        xv += vv;
        __builtin_nontemporal_store(xv, reinterpret_cast<fvec4*>(op + (size_t)r * H));
    }
}

extern "C" void kernel_launch(void* const* d_in, const int* in_sizes, int n_in,
                              void* d_out, int out_size, void* d_ws, size_t ws_size,
                              hipStream_t stream) {
    const float* x     = (const float*)d_in[0];
    const int*   bidx  = (const int*)d_in[1];
    const float* vnode = (const float*)d_in[2];
    const float* W1    = (const float*)d_in[3];
    const float* b1    = (const float*)d_in[4];
    const float* gamma = (const float*)d_in[5];
    const float* beta  = (const float*)d_in[6];
    const float* W2    = (const float*)d_in[7];
    const float* b2    = (const float*)d_in[8];

    const int N = in_sizes[1];            // 500000

    float* out_x  = (float*)d_out;
    float* out_vn = out_x + (size_t)N * H;

    float* ws       = (float*)d_ws;
    float* h0       = ws;                  // B*H
    float* h1       = ws + (size_t)Bg * H; // B*H
    float* colsum   = ws + (size_t)2 * Bg * H;  // H
    float* colsumsq = colsum + H;               // H

    seg_sum_k<<<Bg, 256, 0, stream>>>(x, bidx, vnode, h0, colsum, colsumsq, N);
    gemm1_k<<<Bg / 4, 256, 0, stream>>>(h0, W1, b1, h1, colsum, colsumsq);
    gemm2_k<<<Bg / 4, 256, 0, stream>>>(h1, colsum, colsumsq, gamma, beta, W2, b2, out_vn);

    const int blocks = 2048;
    const int rpb = ((N + blocks - 1) / blocks + 3) & ~3;
    gather_add_k<<<blocks, 256, 0, stream>>>(x, bidx, out_vn, out_x, N, rpb);
}

// Round 3
// 946.908 us; speedup vs baseline: 1.1198x; 1.0024x over previous
//
#include <hip/hip_runtime.h>

#define H 256
#define Bg 1024
#define EPSV 1e-5f

// Native vector type: __builtin_nontemporal_* requires scalar/native-vector.
typedef float fvec4 __attribute__((ext_vector_type(4)));

__device__ __forceinline__ int lower_bound_dev(const int* __restrict__ a, int n, int key) {
    int lo = 0, hi = n;
    while (lo < hi) {
        int mid = (lo + hi) >> 1;
        if (a[mid] < key) lo = mid + 1; else hi = mid;
    }
    return lo;
}

// K1: TWO blocks per graph (row-split halves) -> 2048 blocks = 32 waves/CU
// (max occupancy, 2x the old TLP). 4-deep ILP float4 column sums.
// Partial sums written to partial[2*B][H]; combined (+vnode) in K2.
// Block 0 zeroes BN stat accum (consumed by K2's atomics, next launch).
__global__ void __launch_bounds__(256) seg_sum_k(const float* __restrict__ x,
                                                 const int* __restrict__ bidx,
                                                 float* __restrict__ partial,
                                                 float* __restrict__ colsum,
                                                 float* __restrict__ colsumsq,
                                                 int N) {
    const int bb = blockIdx.x;
    const int b = bb >> 1;
    const int half = bb & 1;
    const int t = threadIdx.x;
    if (bb == 0) { colsum[t] = 0.0f; colsumsq[t] = 0.0f; }

    const int start = lower_bound_dev(bidx, N, b);
    const int end   = lower_bound_dev(bidx, N, b + 1);
    const int mid   = (start + end + 1) >> 1;
    const int s0 = half ? mid : start;
    const int e0 = half ? end : mid;

    const int sub = t >> 6;          // 0..3 : row phase (uniform per wave)
    const int c4  = (t & 63) << 2;   // column group (float4)
    const float* __restrict__ xp = x + c4;

    fvec4 a0 = (fvec4)0.0f;
    fvec4 a1 = a0, a2 = a0, a3 = a0;

    int r = s0 + sub;
    // 4-deep unroll: rows r, r+4, r+8, r+12 (stride 4 = phase stride).
    for (; r + 12 < e0; r += 16) {
        const fvec4 v0 = __builtin_nontemporal_load(
            reinterpret_cast<const fvec4*>(xp + (size_t)r * H));
        const fvec4 v1 = __builtin_nontemporal_load(
            reinterpret_cast<const fvec4*>(xp + (size_t)(r + 4) * H));
        const fvec4 v2 = __builtin_nontemporal_load(
            reinterpret_cast<const fvec4*>(xp + (size_t)(r + 8) * H));
        const fvec4 v3 = __builtin_nontemporal_load(
            reinterpret_cast<const fvec4*>(xp + (size_t)(r + 12) * H));
        a0 += v0; a1 += v1; a2 += v2; a3 += v3;
    }
    for (; r < e0; r += 4) {
        const fvec4 v = __builtin_nontemporal_load(
            reinterpret_cast<const fvec4*>(xp + (size_t)r * H));
        a0 += v;
    }

    const fvec4 acc = (a0 + a1) + (a2 + a3);

    __shared__ fvec4 red[256];
    red[t] = acc;
    __syncthreads();
    if (sub == 0) {
        fvec4 s = red[t];
        s += red[t + 64];
        s += red[t + 128];
        s += red[t + 192];
        *reinterpret_cast<fvec4*>(partial + (size_t)bb * H + c4) = s;
    }
}

// K2: h1 = (p0+p1+vnode) @ W1 + b1 ([1024,256]x[256,256]); 4 rows per block,
// W1 streamed coalesced (L2-resident). Also accumulates BN column sum/sumsq.
__global__ void __launch_bounds__(256) gemm1_k(const float* __restrict__ partial,
                                               const float* __restrict__ vnode,
                                               const float* __restrict__ W1,
                                               const float* __restrict__ b1,
                                               float* __restrict__ h1,
                                               float* __restrict__ colsum,
                                               float* __restrict__ colsumsq) {
    __shared__ float a[4][H];
    const int t = threadIdx.x;
    const int r0 = blockIdx.x << 2;
#pragma unroll
    for (int i = 0; i < 4; ++i) {
        const int r = r0 + i;
        a[i][t] = partial[(size_t)(2 * r) * H + t]
                + partial[(size_t)(2 * r + 1) * H + t]
                + vnode[(size_t)r * H + t];
    }
    __syncthreads();

    const float bb = b1[t];
    float acc0 = bb, acc1 = bb, acc2 = bb, acc3 = bb;
#pragma unroll 8
    for (int k = 0; k < H; ++k) {
        const float w = W1[(size_t)k * H + t];   // coalesced across t, broadcast a[][k]
        acc0 = fmaf(a[0][k], w, acc0);
        acc1 = fmaf(a[1][k], w, acc1);
        acc2 = fmaf(a[2][k], w, acc2);
        acc3 = fmaf(a[3][k], w, acc3);
    }
    h1[(size_t)(r0 + 0) * H + t] = acc0;
    h1[(size_t)(r0 + 1) * H + t] = acc1;
    h1[(size_t)(r0 + 2) * H + t] = acc2;
    h1[(size_t)(r0 + 3) * H + t] = acc3;

    const float s  = acc0 + acc1 + acc2 + acc3;
    const float sq = acc0 * acc0 + acc1 * acc1 + acc2 * acc2 + acc3 * acc3;
    atomicAdd(&colsum[t], s);
    atomicAdd(&colsumsq[t], sq);
}

// K3: vn = relu(BN(h1)) @ W2 + b2. BN applied on the fly from colsum/colsumsq.
// vn written directly to d_out's second output slot.
__global__ void __launch_bounds__(256) gemm2_k(const float* __restrict__ h1,
                                               const float* __restrict__ colsum,
                                               const float* __restrict__ colsumsq,
                                               const float* __restrict__ gamma,
                                               const float* __restrict__ beta,
                                               const float* __restrict__ W2,
                                               const float* __restrict__ b2,
                                               float* __restrict__ out_vn) {
    __shared__ float a[4][H];
    const int t = threadIdx.x;
    const int r0 = blockIdx.x << 2;

    const float invB = 1.0f / (float)Bg;
    const float m   = colsum[t] * invB;
    const float var = colsumsq[t] * invB - m * m;
    const float g   = gamma[t] * rsqrtf(var + EPSV);
    const float be  = beta[t];

#pragma unroll
    for (int i = 0; i < 4; ++i) {
        float v = h1[(size_t)(r0 + i) * H + t];
        v = (v - m) * g + be;
        a[i][t] = fmaxf(v, 0.0f);
    }
    __syncthreads();

    const float bb = b2[t];
    float acc0 = bb, acc1 = bb, acc2 = bb, acc3 = bb;
#pragma unroll 8
    for (int k = 0; k < H; ++k) {
        const float w = W2[(size_t)k * H + t];
        acc0 = fmaf(a[0][k], w, acc0);
        acc1 = fmaf(a[1][k], w, acc1);
        acc2 = fmaf(a[2][k], w, acc2);
        acc3 = fmaf(a[3][k], w, acc3);
    }
    out_vn[(size_t)(r0 + 0) * H + t] = acc0;
    out_vn[(size_t)(r0 + 1) * H + t] = acc1;
    out_vn[(size_t)(r0 + 2) * H + t] = acc2;
    out_vn[(size_t)(r0 + 3) * H + t] = acc3;
}

// K4: x_out = x + vn[batch_idx]. Contiguous row chunks per block, float4,
// 4-deep ILP (all 4 x-loads + 4 vn-gathers issued before any adds/stores).
// Nontemporal x read / x_out write (no reuse; 512MB >> L3). vn stays cached.
__global__ void __launch_bounds__(256) gather_add_k(const float* __restrict__ x,
                                                    const int* __restrict__ bidx,
                                                    const float* __restrict__ vn,
                                                    float* __restrict__ xout,
                                                    int N, int rpb) {
    const int t = threadIdx.x;
    const int r0 = blockIdx.x * rpb;
    const int r1 = min(N, r0 + rpb);
    const int sub = t >> 6;          // uniform per wave
    const int c4  = (t & 63) << 2;
    const float* __restrict__ xp = x + c4;
    float* __restrict__ op = xout + c4;

    int r = r0 + sub;
    for (; r + 12 < r1; r += 16) {
        const int b0 = bidx[r];
        const int b1 = bidx[r + 4];
        const int b2 = bidx[r + 8];
        const int b3 = bidx[r + 12];
        fvec4 x0 = __builtin_nontemporal_load(
            reinterpret_cast<const fvec4*>(xp + (size_t)r * H));
        fvec4 x1 = __builtin_nontemporal_load(
            reinterpret_cast<const fvec4*>(xp + (size_t)(r + 4) * H));
        fvec4 x2 = __builtin_nontemporal_load(
            reinterpret_cast<const fvec4*>(xp + (size_t)(r + 8) * H));
        fvec4 x3 = __builtin_nontemporal_load(
            reinterpret_cast<const fvec4*>(xp + (size_t)(r + 12) * H));
        const fvec4 v0 = *reinterpret_cast<const fvec4*>(vn + (size_t)b0 * H + c4);
        const fvec4 v1 = *reinterpret_cast<const fvec4*>(vn + (size_t)b1 * H + c4);
        const fvec4 v2 = *reinterpret_cast<const fvec4*>(vn + (size_t)b2 * H + c4);
        const fvec4 v3 = *reinterpret_cast<const fvec4*>(vn + (size_t)b3 * H + c4);
        x0 += v0; x1 += v1; x2 += v2; x3 += v3;
        __builtin_nontemporal_store(x0, reinterpret_cast<fvec4*>(op + (size_t)r * H));
        __builtin_nontemporal_store(x1, reinterpret_cast<fvec4*>(op + (size_t)(r + 4) * H));
        __builtin_nontemporal_store(x2, reinterpret_cast<fvec4*>(op + (size_t)(r + 8) * H));
        __builtin_nontemporal_store(x3, reinterpret_cast<fvec4*>(op + (size_t)(r + 12) * H));
    }
    for (; r < r1; r += 4) {
        const int b = bidx[r];
        fvec4 xv = __builtin_nontemporal_load(
            reinterpret_cast<const fvec4*>(xp + (size_t)r * H));
        const fvec4 vv = *reinterpret_cast<const fvec4*>(vn + (size_t)b * H + c4);
        xv += vv;
        __builtin_nontemporal_store(xv, reinterpret_cast<fvec4*>(op + (size_t)r * H));
    }
}

extern "C" void kernel_launch(void* const* d_in, const int* in_sizes, int n_in,
                              void* d_out, int out_size, void* d_ws, size_t ws_size,
                              hipStream_t stream) {
    const float* x     = (const float*)d_in[0];
    const int*   bidx  = (const int*)d_in[1];
    const float* vnode = (const float*)d_in[2];
    const float* W1    = (const float*)d_in[3];
    const float* b1    = (const float*)d_in[4];
    const float* gamma = (const float*)d_in[5];
    const float* beta  = (const float*)d_in[6];
    const float* W2    = (const float*)d_in[7];
    const float* b2    = (const float*)d_in[8];

    const int N = in_sizes[1];            // 500000

    float* out_x  = (float*)d_out;
    float* out_vn = out_x + (size_t)N * H;

    float* ws       = (float*)d_ws;
    float* partial  = ws;                       // 2*B*H
    float* h1       = ws + (size_t)2 * Bg * H;  // B*H
    float* colsum   = ws + (size_t)3 * Bg * H;  // H
    float* colsumsq = colsum + H;               // H

    seg_sum_k<<<2 * Bg, 256, 0, stream>>>(x, bidx, partial, colsum, colsumsq, N);
    gemm1_k<<<Bg / 4, 256, 0, stream>>>(partial, vnode, W1, b1, h1, colsum, colsumsq);
    gemm2_k<<<Bg / 4, 256, 0, stream>>>(h1, colsum, colsumsq, gamma, beta, W2, b2, out_vn);

    const int blocks = 2048;
    const int rpb = ((N + blocks - 1) / blocks + 3) & ~3;
    gather_add_k<<<blocks, 256, 0, stream>>>(x, bidx, out_vn, out_x, N, rpb);
}